// Round 5
// baseline (615.165 us; speedup 1.0000x reference)
//
#include <hip/hip_runtime.h>

#define Bb 64
#define Tt 12
#define Nn 512
#define Dd 2
#define G3 192
#define Hh 12
#define CSR_CAP 96

typedef float f32x4 __attribute__((ext_vector_type(4)));
typedef _Float16 f16;
typedef _Float16 f16x8 __attribute__((ext_vector_type(8)));

// XOR swizzle for 64x64 fp32 LDS tile (row stride 256B), 16B-granular.
__device__ __forceinline__ int swz4(int row, int bo) {
  return row * 256 + (bo ^ ((row & 7) << 4));
}

// ---------------------------------------------------------------------------
// init: zero-padded CSR of each adjacency column; fp16 fragment-packed weights.
// g_blob layout: [0,57344) f16 frags (W_ih^T | W_hh^T @12288 | W_msg^T @24576)
//                [57344,60672) fp32 extras (sWx | b_ih | b_hh | b_msg)
//                [60672,61440) pad (staged, never read)
// ---------------------------------------------------------------------------
__global__ __launch_bounds__(256) void init_kernel(
    const float* __restrict__ adj, const float* __restrict__ W_msg,
    const float* __restrict__ W_ih, const float* __restrict__ W_hh,
    const float* __restrict__ b_ih, const float* __restrict__ b_hh,
    const float* __restrict__ b_msg, f16* __restrict__ g_w,
    float* __restrict__ g_f, int* __restrict__ g_cj,
    float* __restrict__ g_ca, int* __restrict__ g_nnz) {
  __shared__ int s_wavecnt[4];
  const int n = blockIdx.x, tid = threadIdx.x, l = tid & 63, wt = tid >> 6;

  // zero-fill CSR (pad entries read by the unroll-2 gather: j=0, a=0)
  if (tid < CSR_CAP) {
    g_cj[n * CSR_CAP + tid] = 0;
    g_ca[n * CSR_CAP + tid] = 0.f;
  }

  // CSR of column n (deterministic ballot prefix-scan)
  {
    const int j0 = tid * 2, j1 = j0 + 1;
    const float a0 = adj[j0 * Nn + n];
    const float a1 = adj[j1 * Nn + n];
    unsigned long long mk0 = __ballot(a0 > 0.f);
    unsigned long long mk1 = __ballot(a1 > 0.f);
    if (l == 0) s_wavecnt[wt] = __popcll(mk0) + __popcll(mk1);
    __syncthreads();   // also orders the zero-fill before the scatter below
    int base = 0;
#pragma unroll
    for (int w = 0; w < 4; ++w)
      if (w < wt) base += s_wavecnt[w];
    unsigned long long lt = (1ull << l) - 1ull;
    int pos = base + __popcll(mk0 & lt) + __popcll(mk1 & lt);
    if (a0 > 0.f) {
      if (pos < CSR_CAP) { g_cj[n * CSR_CAP + pos] = j0; g_ca[n * CSR_CAP + pos] = a0; }
      ++pos;
    }
    if (a1 > 0.f && pos < CSR_CAP) { g_cj[n * CSR_CAP + pos] = j1; g_ca[n * CSR_CAP + pos] = a1; }
    if (tid == 0) {
      int tot = s_wavecnt[0] + s_wavecnt[1] + s_wavecnt[2] + s_wavecnt[3];
      g_nnz[n] = tot < CSR_CAP ? tot : CSR_CAP;
    }
  }

  // weight fragment packing (block 0 only)
  // frag (nt,kt): lane l elem j holds W[nt*16+(l&15)][kt*32+8*(l>>4)+j]
  if (n == 0) {
    for (int tile = wt; tile < 24; tile += 4) {
      const int nt = tile >> 1, kt = tile & 1;
      const int wrow = nt * 16 + (l & 15);
      const int kc = kt * 32 + ((l >> 4) << 3);
      const float* s2 = W_ih + wrow * 66 + kc;
      const float* s1 = W_hh + wrow * 64 + kc;
#pragma unroll
      for (int j = 0; j < 8; ++j) {
        g_w[tile * 512 + l * 8 + j] = (f16)s2[j];
        g_w[12288 + tile * 512 + l * 8 + j] = (f16)s1[j];
      }
    }
    for (int tile = wt; tile < 8; tile += 4) {
      const int nt = tile >> 1, kt = tile & 1;
      const int wrow = nt * 16 + (l & 15);
      const int kc = kt * 32 + ((l >> 4) << 3);
      const float* s1 = W_msg + wrow * 64 + kc;
#pragma unroll
      for (int j = 0; j < 8; ++j) g_w[24576 + tile * 512 + l * 8 + j] = (f16)s1[j];
    }
    if (tid < G3) {
      g_f[tid * 2] = W_ih[tid * 66 + 64];
      g_f[tid * 2 + 1] = W_ih[tid * 66 + 65];
      g_f[384 + tid] = b_ih[tid];
      g_f[576 + tid] = b_hh[tid];
    }
    if (tid < 64) g_f[768 + tid] = b_msg[tid];
  }
}

// ---------------------------------------------------------------------------
// hw0 = h0 @ W_msg^T + b_msg  (split-fp16 A; fp32 out; W frags from global)
// ---------------------------------------------------------------------------
__global__ __launch_bounds__(256) void hw0_kernel(
    const float* __restrict__ h0, const f16* __restrict__ g_w,
    const float* __restrict__ g_f, float* __restrict__ hw_out) {
  __shared__ float h_lds[4096];
  const int n = blockIdx.x, tid = threadIdx.x, l = tid & 63, wt = tid >> 6;
  {
    const int row = tid >> 2, c0 = (tid & 3) << 4;
    const float4* src = (const float4*)(h0 + ((n << 6) + row) * 64 + c0);
#pragma unroll
    for (int q = 0; q < 4; ++q)
      *(float4*)((char*)h_lds + swz4(row, c0 * 4 + q * 16)) = src[q];
  }
  // own-wave rows only -> no barrier
  const int ar = wt * 16 + (l & 15);
  const int bo = (l >> 4) << 5;
  f16x8 ahi0, alo0, ahi1, alo1;
  {
    float4 p0 = *(const float4*)((const char*)h_lds + swz4(ar, bo));
    float4 p1 = *(const float4*)((const char*)h_lds + swz4(ar, bo + 16));
    float4 p2 = *(const float4*)((const char*)h_lds + swz4(ar, 128 + bo));
    float4 p3 = *(const float4*)((const char*)h_lds + swz4(ar, 128 + bo + 16));
    float v[16] = {p0.x, p0.y, p0.z, p0.w, p1.x, p1.y, p1.z, p1.w,
                   p2.x, p2.y, p2.z, p2.w, p3.x, p3.y, p3.z, p3.w};
#pragma unroll
    for (int j = 0; j < 8; ++j) {
      f16 h = (f16)v[j];        ahi0[j] = h; alo0[j] = (f16)(v[j] - (float)h);
      f16 g = (f16)v[8 + j];    ahi1[j] = g; alo1[j] = (f16)(v[8 + j] - (float)g);
    }
  }
#pragma unroll
  for (int nt = 0; nt < 4; ++nt) {
    const f16x8 b0 = *(const f16x8*)(g_w + 24576 + (nt * 2 + 0) * 512 + l * 8);
    const f16x8 b1 = *(const f16x8*)(g_w + 24576 + (nt * 2 + 1) * 512 + l * 8);
    f32x4 c = {0.f, 0.f, 0.f, 0.f};
    c = __builtin_amdgcn_mfma_f32_16x16x32_f16(ahi0, b0, c, 0, 0, 0);
    c = __builtin_amdgcn_mfma_f32_16x16x32_f16(alo0, b0, c, 0, 0, 0);
    c = __builtin_amdgcn_mfma_f32_16x16x32_f16(ahi1, b1, c, 0, 0, 0);
    c = __builtin_amdgcn_mfma_f32_16x16x32_f16(alo1, b1, c, 0, 0, 0);
    const int col = nt * 16 + (l & 15);
    const float bm = g_f[768 + col];
#pragma unroll
    for (int g = 0; g < 4; ++g) {
      const int row = wt * 16 + ((l >> 4) << 2) + g;
      hw_out[((n << 6) + row) * 64 + col] = c[g] + bm;
    }
  }
}

// ---------------------------------------------------------------------------
// one GRU message-passing step (block = node n); t==11 folds the output GEMM
// ---------------------------------------------------------------------------
__global__ __launch_bounds__(256, 2) void step_kernel(
    const float* __restrict__ xin, const float* __restrict__ h_src,
    float* __restrict__ h_ws, const uint4* __restrict__ g_blob,
    const int* __restrict__ g_cj, const float* __restrict__ g_ca,
    const int* __restrict__ g_nnz, const float* __restrict__ hw_rd,
    float* __restrict__ hw_wr, const float* __restrict__ W_out,
    const float* __restrict__ b_out, float* __restrict__ out, int t) {
  __shared__ uint4 sBlob[3840];   // 61440B: f16 hi-frags + fp32 extras + pad
  __shared__ float h_lds[4096];   // h fp32, swizzled; rows are wave-owned
  const f16* sBih = (const f16*)sBlob;
  const f16* sBhh = sBih + 12288;
  const f16* sBmsg = sBih + 24576;
  const float* sF = (const float*)(sBih + 28672);
  const float* sWx = sF;          // [384]
  const float* s_bih = sF + 384;
  const float* s_bhh = sF + 576;
  const float* s_bmsg = sF + 768;

  const int n = blockIdx.x, tid = threadIdx.x, l = tid & 63, wt = tid >> 6;

  // --- front-loaded independent loads ---
  float x0[4], x1[4];
#pragma unroll
  for (int g = 0; g < 4; ++g) {
    const int brow = wt * 16 + ((l >> 4) << 2) + g;   // batch index
    const float2 xv = *(const float2*)(xin + ((brow * Tt + t) * Nn + n) * Dd);
    x0[g] = xv.x; x1[g] = xv.y;
  }
  float hreg[4][4];   // fp32 carry in MFMA C layout
#pragma unroll
  for (int ct = 0; ct < 4; ++ct)
#pragma unroll
    for (int g = 0; g < 4; ++g) {
      const int row = wt * 16 + ((l >> 4) << 2) + g;
      hreg[ct][g] = h_src[((n << 6) + row) * 64 + ct * 16 + (l & 15)];
    }
  {
    const int row = tid >> 2, c0 = (tid & 3) << 4;   // wave-owned rows
    const float4* src = (const float4*)(h_src + ((n << 6) + row) * 64 + c0);
#pragma unroll
    for (int q = 0; q < 4; ++q)
      *(float4*)((char*)h_lds + swz4(row, c0 * 4 + q * 16)) = src[q];
  }
  for (int i = tid; i < 3840; i += 256) sBlob[i] = g_blob[i];

  // --- gather m directly in A-frag register layout (pre-barrier, fp32 hw) ---
  // lane owns m[b = 16wt+(l&15)][8*(l>>4)+j (+32 for ktile1)]
  const int mb = wt * 16 + (l & 15);
  const int mc0 = (l >> 4) << 3;
  const float* hwbase = hw_rd + mb * 64 + mc0;
  float accm[16];
#pragma unroll
  for (int e = 0; e < 16; ++e) accm[e] = 0.f;
  const int nnz = g_nnz[n];
  for (int k = 0; k < nnz; k += 2) {   // CSR zero-padded: odd tail safe
    const int2 j2 = *(const int2*)(g_cj + n * CSR_CAP + k);
    const float2 a2 = *(const float2*)(g_ca + n * CSR_CAP + k);
    const float4* p0 = (const float4*)(hwbase + ((size_t)j2.x << 12));
    const float4* p1 = (const float4*)(hwbase + ((size_t)j2.y << 12));
    const float4 u0 = p0[0], u1 = p0[1], u2 = p0[8], u3 = p0[9];
    const float4 v0 = p1[0], v1 = p1[1], v2 = p1[8], v3 = p1[9];
    const float ax = a2.x, ay = a2.y;
    accm[0] += ax * u0.x + ay * v0.x;  accm[1] += ax * u0.y + ay * v0.y;
    accm[2] += ax * u0.z + ay * v0.z;  accm[3] += ax * u0.w + ay * v0.w;
    accm[4] += ax * u1.x + ay * v1.x;  accm[5] += ax * u1.y + ay * v1.y;
    accm[6] += ax * u1.z + ay * v1.z;  accm[7] += ax * u1.w + ay * v1.w;
    accm[8] += ax * u2.x + ay * v2.x;  accm[9] += ax * u2.y + ay * v2.y;
    accm[10] += ax * u2.z + ay * v2.z; accm[11] += ax * u2.w + ay * v2.w;
    accm[12] += ax * u3.x + ay * v3.x; accm[13] += ax * u3.y + ay * v3.y;
    accm[14] += ax * u3.z + ay * v3.z; accm[15] += ax * u3.w + ay * v3.w;
  }
  f16x8 mhi0, mlo0, mhi1, mlo1;
#pragma unroll
  for (int j = 0; j < 8; ++j) {
    f16 h = (f16)accm[j];      mhi0[j] = h; mlo0[j] = (f16)(accm[j] - (float)h);
    f16 g = (f16)accm[8 + j];  mhi1[j] = g; mlo1[j] = (f16)(accm[8 + j] - (float)g);
  }
  __syncthreads();   // sBlob ready (cross-wave)

  // h(t) A-frags hi/lo
  const int ar = wt * 16 + (l & 15);
  const int bo = (l >> 4) << 5;
  f16x8 ahi0, alo0, ahi1, alo1;
  {
    float4 p0 = *(const float4*)((const char*)h_lds + swz4(ar, bo));
    float4 p1 = *(const float4*)((const char*)h_lds + swz4(ar, bo + 16));
    float4 p2 = *(const float4*)((const char*)h_lds + swz4(ar, 128 + bo));
    float4 p3 = *(const float4*)((const char*)h_lds + swz4(ar, 128 + bo + 16));
    float v[16] = {p0.x, p0.y, p0.z, p0.w, p1.x, p1.y, p1.z, p1.w,
                   p2.x, p2.y, p2.z, p2.w, p3.x, p3.y, p3.z, p3.w};
#pragma unroll
    for (int j = 0; j < 8; ++j) {
      f16 h = (f16)v[j];        ahi0[j] = h; alo0[j] = (f16)(v[j] - (float)h);
      f16 g = (f16)v[8 + j];    ahi1[j] = g; alo1[j] = (f16)(v[8 + j] - (float)g);
    }
  }

  // gi = m @ W_ih^T ; gh = h @ W_hh^T  (act-split fp16, fp32 accum)
  f32x4 cgi[12], cgh[12];
#pragma unroll
  for (int nt = 0; nt < 12; ++nt) {
    cgi[nt] = {0.f, 0.f, 0.f, 0.f};
    cgh[nt] = {0.f, 0.f, 0.f, 0.f};
  }
#pragma unroll
  for (int nt = 0; nt < 12; ++nt) {
    const f16x8 bh0 = *(const f16x8*)(sBhh + (nt * 2 + 0) * 512 + l * 8);
    const f16x8 bh1 = *(const f16x8*)(sBhh + (nt * 2 + 1) * 512 + l * 8);
    cgh[nt] = __builtin_amdgcn_mfma_f32_16x16x32_f16(ahi0, bh0, cgh[nt], 0, 0, 0);
    cgh[nt] = __builtin_amdgcn_mfma_f32_16x16x32_f16(alo0, bh0, cgh[nt], 0, 0, 0);
    cgh[nt] = __builtin_amdgcn_mfma_f32_16x16x32_f16(ahi1, bh1, cgh[nt], 0, 0, 0);
    cgh[nt] = __builtin_amdgcn_mfma_f32_16x16x32_f16(alo1, bh1, cgh[nt], 0, 0, 0);
    const f16x8 bi0 = *(const f16x8*)(sBih + (nt * 2 + 0) * 512 + l * 8);
    const f16x8 bi1 = *(const f16x8*)(sBih + (nt * 2 + 1) * 512 + l * 8);
    cgi[nt] = __builtin_amdgcn_mfma_f32_16x16x32_f16(mhi0, bi0, cgi[nt], 0, 0, 0);
    cgi[nt] = __builtin_amdgcn_mfma_f32_16x16x32_f16(mlo0, bi0, cgi[nt], 0, 0, 0);
    cgi[nt] = __builtin_amdgcn_mfma_f32_16x16x32_f16(mhi1, bi1, cgi[nt], 0, 0, 0);
    cgi[nt] = __builtin_amdgcn_mfma_f32_16x16x32_f16(mlo1, bi1, cgi[nt], 0, 0, 0);
  }

  // GRU gates (fp32): update carry, h_ws, h_lds (own-wave rows)
#pragma unroll
  for (int ct = 0; ct < 4; ++ct) {
    const int colr = ct * 16 + (l & 15);
    const float wr0 = sWx[colr * 2], wr1 = sWx[colr * 2 + 1];
    const float wz0 = sWx[(colr + 64) * 2], wz1 = sWx[(colr + 64) * 2 + 1];
    const float wn0 = sWx[(colr + 128) * 2], wn1 = sWx[(colr + 128) * 2 + 1];
    const float bir = s_bih[colr], biz = s_bih[colr + 64], bin_ = s_bih[colr + 128];
    const float bhr = s_bhh[colr], bhz = s_bhh[colr + 64], bhn = s_bhh[colr + 128];
#pragma unroll
    for (int g = 0; g < 4; ++g) {
      const int row = wt * 16 + ((l >> 4) << 2) + g;
      const float gir = cgi[ct][g] + x0[g] * wr0 + x1[g] * wr1 + bir;
      const float giz = cgi[ct + 4][g] + x0[g] * wz0 + x1[g] * wz1 + biz;
      const float gin = cgi[ct + 8][g] + x0[g] * wn0 + x1[g] * wn1 + bin_;
      const float ghr = cgh[ct][g] + bhr;
      const float ghz = cgh[ct + 4][g] + bhz;
      const float ghn = cgh[ct + 8][g] + bhn;
      const float rg = 1.f / (1.f + __expf(-(gir + ghr)));
      const float zg = 1.f / (1.f + __expf(-(giz + ghz)));
      const float pa = gin + rg * ghn;
      const float e2 = __expf(-2.f * fabsf(pa));
      float th = (1.f - e2) / (1.f + e2);
      th = copysignf(th, pa);
      const float hn = (1.f - zg) * th + zg * hreg[ct][g];
      h_ws[((n << 6) + row) * 64 + colr] = hn;
      *(float*)((char*)h_lds + swz4(row, colr * 4)) = hn;
    }
  }

  if (t < Tt - 1) {
    // hw(t+1) = h(t+1) @ W_msg^T + b_msg (own-wave h_lds rows; fp32 store)
    f16x8 nhi0, nlo0, nhi1, nlo1;
    {
      float4 p0 = *(const float4*)((const char*)h_lds + swz4(ar, bo));
      float4 p1 = *(const float4*)((const char*)h_lds + swz4(ar, bo + 16));
      float4 p2 = *(const float4*)((const char*)h_lds + swz4(ar, 128 + bo));
      float4 p3 = *(const float4*)((const char*)h_lds + swz4(ar, 128 + bo + 16));
      float v[16] = {p0.x, p0.y, p0.z, p0.w, p1.x, p1.y, p1.z, p1.w,
                     p2.x, p2.y, p2.z, p2.w, p3.x, p3.y, p3.z, p3.w};
#pragma unroll
      for (int j = 0; j < 8; ++j) {
        f16 h = (f16)v[j];        nhi0[j] = h; nlo0[j] = (f16)(v[j] - (float)h);
        f16 g = (f16)v[8 + j];    nhi1[j] = g; nlo1[j] = (f16)(v[8 + j] - (float)g);
      }
    }
#pragma unroll
    for (int nt = 0; nt < 4; ++nt) {
      const f16x8 b0 = *(const f16x8*)(sBmsg + (nt * 2 + 0) * 512 + l * 8);
      const f16x8 b1 = *(const f16x8*)(sBmsg + (nt * 2 + 1) * 512 + l * 8);
      f32x4 c = {0.f, 0.f, 0.f, 0.f};
      c = __builtin_amdgcn_mfma_f32_16x16x32_f16(nhi0, b0, c, 0, 0, 0);
      c = __builtin_amdgcn_mfma_f32_16x16x32_f16(nlo0, b0, c, 0, 0, 0);
      c = __builtin_amdgcn_mfma_f32_16x16x32_f16(nhi1, b1, c, 0, 0, 0);
      c = __builtin_amdgcn_mfma_f32_16x16x32_f16(nlo1, b1, c, 0, 0, 0);
      const int col = nt * 16 + (l & 15);
      const float bm = s_bmsg[col];
#pragma unroll
      for (int g = 0; g < 4; ++g) {
        const int row = wt * 16 + ((l >> 4) << 2) + g;
        hw_wr[((n << 6) + row) * 64 + col] = c[g] + bm;
      }
    }
  } else {
    // out[b,o,n,0] = h[n,b,:] . W_out[o,:] + b_out[o]  (one MFMA pair)
    __syncthreads();   // h_lds fully updated across waves
    const int col = l & 15;             // o (cols 12..15 padded)
    const int kc = (l >> 4) << 3;
    f16x8 wo0 = {0, 0, 0, 0, 0, 0, 0, 0}, wo1 = {0, 0, 0, 0, 0, 0, 0, 0};
    if (col < Hh) {
      const float* wr_ = W_out + col * 64 + kc;
      const float4 w0 = *(const float4*)(wr_);
      const float4 w1 = *(const float4*)(wr_ + 4);
      const float4 w2 = *(const float4*)(wr_ + 32);
      const float4 w3 = *(const float4*)(wr_ + 36);
      wo0[0] = (f16)w0.x; wo0[1] = (f16)w0.y; wo0[2] = (f16)w0.z; wo0[3] = (f16)w0.w;
      wo0[4] = (f16)w1.x; wo0[5] = (f16)w1.y; wo0[6] = (f16)w1.z; wo0[7] = (f16)w1.w;
      wo1[0] = (f16)w2.x; wo1[1] = (f16)w2.y; wo1[2] = (f16)w2.z; wo1[3] = (f16)w2.w;
      wo1[4] = (f16)w3.x; wo1[5] = (f16)w3.y; wo1[6] = (f16)w3.z; wo1[7] = (f16)w3.w;
    }
    f16x8 hh0, hh1;
    {
      float4 p0 = *(const float4*)((const char*)h_lds + swz4(ar, bo));
      float4 p1 = *(const float4*)((const char*)h_lds + swz4(ar, bo + 16));
      float4 p2 = *(const float4*)((const char*)h_lds + swz4(ar, 128 + bo));
      float4 p3 = *(const float4*)((const char*)h_lds + swz4(ar, 128 + bo + 16));
      hh0[0] = (f16)p0.x; hh0[1] = (f16)p0.y; hh0[2] = (f16)p0.z; hh0[3] = (f16)p0.w;
      hh0[4] = (f16)p1.x; hh0[5] = (f16)p1.y; hh0[6] = (f16)p1.z; hh0[7] = (f16)p1.w;
      hh1[0] = (f16)p2.x; hh1[1] = (f16)p2.y; hh1[2] = (f16)p2.z; hh1[3] = (f16)p2.w;
      hh1[4] = (f16)p3.x; hh1[5] = (f16)p3.y; hh1[6] = (f16)p3.z; hh1[7] = (f16)p3.w;
    }
    f32x4 c = {0.f, 0.f, 0.f, 0.f};
    c = __builtin_amdgcn_mfma_f32_16x16x32_f16(hh0, wo0, c, 0, 0, 0);
    c = __builtin_amdgcn_mfma_f32_16x16x32_f16(hh1, wo1, c, 0, 0, 0);
    if (col < Hh) {
      const float bo_ = b_out[col];
#pragma unroll
      for (int g = 0; g < 4; ++g) {
        const int row = wt * 16 + ((l >> 4) << 2) + g;   // batch b
        out[(row * Hh + col) * Nn + n] = c[g] + bo_;
      }
    }
  }
}

extern "C" void kernel_launch(void* const* d_in, const int* in_sizes, int n_in,
                              void* d_out, int out_size, void* d_ws, size_t ws_size,
                              hipStream_t stream) {
  const float* xin = (const float*)d_in[0];
  const float* h0 = (const float*)d_in[1];
  const float* adj = (const float*)d_in[2];
  const float* W_msg = (const float*)d_in[3];
  const float* b_msg = (const float*)d_in[4];
  const float* W_ih = (const float*)d_in[5];
  const float* W_hh = (const float*)d_in[6];
  const float* b_ih = (const float*)d_in[7];
  const float* b_hh = (const float*)d_in[8];
  const float* W_out = (const float*)d_in[9];
  const float* b_out = (const float*)d_in[10];
  float* out = (float*)d_out;

  // ws: [0,8M) h fp32 | [8M,16M) hwA fp32 | [16M,24M) hwB fp32 |
  //     24M: g_blob 61440B | +61440: g_cj | +196608: g_ca | +196608: g_nnz
  char* ws = (char*)d_ws;
  float* h_ws = (float*)ws;
  float* hwA = (float*)(ws + (8u << 20));
  float* hwB = (float*)(ws + (16u << 20));
  char* base = ws + (24u << 20);
  f16* g_w = (f16*)base;
  float* g_f = (float*)(base + 57344);
  int* g_cj = (int*)(base + 61440);
  float* g_ca = (float*)(base + 61440 + 196608);
  int* g_nnz = (int*)(base + 61440 + 393216);
  const uint4* g_blob = (const uint4*)base;

  init_kernel<<<Nn, 256, 0, stream>>>(adj, W_msg, W_ih, W_hh, b_ih, b_hh,
                                      b_msg, g_w, g_f, g_cj, g_ca, g_nnz);
  hw0_kernel<<<Nn, 256, 0, stream>>>(h0, g_w, g_f, hwA);
  for (int t = 0; t < Tt; ++t) {
    const float* rd = (t & 1) ? hwB : hwA;
    float* wr = (t & 1) ? hwA : hwB;
    const float* hs = (t == 0) ? h0 : h_ws;
    step_kernel<<<Nn, 256, 0, stream>>>(xin, hs, h_ws, g_blob, g_cj, g_ca,
                                        g_nnz, rd, wr, W_out, b_out, out, t);
  }
}

// Round 6
// 489.071 us; speedup vs baseline: 1.2578x; 1.2578x over previous
//
#include <hip/hip_runtime.h>

#define Bb 64
#define Tt 12
#define Nn 512
#define Dd 2
#define G3 192
#define Hh 12

typedef float f32x4 __attribute__((ext_vector_type(4)));
typedef _Float16 f16;
typedef _Float16 f16x8 __attribute__((ext_vector_type(8)));

// XOR swizzle for 64x64 fp32 LDS tile (row stride 256B), 16B-granular.
__device__ __forceinline__ int swz4(int row, int bo) {
  return row * 256 + (bo ^ ((row & 7) << 4));
}

// ---------------------------------------------------------------------------
// init: A_pos^T hi/lo fp16 fragments (exact split), rowsum, fp16 weight frags.
// g_atf[((it*16+kt)*2+plane)*512 + l*8 + e] = adjpos[j=kt*32+8*(l>>4)+e][i=it*16+(l&15)]
// g_blob: [0,57344) f16 frags (W_ih^T | W_hh^T @12288 | W_msg^T @24576)
//         [57344,60672) fp32 extras (sWx | b_ih | b_hh | b_msg)
// ---------------------------------------------------------------------------
__global__ __launch_bounds__(256) void init_kernel(
    const float* __restrict__ adj, const float* __restrict__ W_msg,
    const float* __restrict__ W_ih, const float* __restrict__ W_hh,
    const float* __restrict__ b_ih, const float* __restrict__ b_hh,
    const float* __restrict__ b_msg, f16* __restrict__ g_atf,
    float* __restrict__ g_rowsum, f16* __restrict__ g_w,
    float* __restrict__ g_f) {
  const int bid = blockIdx.x, tid = threadIdx.x, l = tid & 63, wt = tid >> 6;
  if (bid < 32) {
    const int it = bid;
    for (int kt = wt; kt < 16; kt += 4) {
      const int i = (it << 4) + (l & 15);
      const int j0 = (kt << 5) + ((l >> 4) << 3);
      f16* dhi = g_atf + ((it * 16 + kt) * 2 + 0) * 512 + l * 8;
      f16* dlo = g_atf + ((it * 16 + kt) * 2 + 1) * 512 + l * 8;
#pragma unroll
      for (int e = 0; e < 8; ++e) {
        float a = adj[(j0 + e) * Nn + i];
        a = a > 0.f ? a : 0.f;
        const f16 h = (f16)a;
        dhi[e] = h;
        dlo[e] = (f16)(a - (float)h);
      }
    }
    // rowsum[i] = sum_j adjpos[j][i]
    {
      const int i = (it << 4) + (tid >> 4);
      float rs = 0.f;
      for (int j = (tid & 15); j < Nn; j += 16) {
        const float a = adj[j * Nn + i];
        rs += (a > 0.f ? a : 0.f);
      }
      for (int off = 8; off; off >>= 1) rs += __shfl_down(rs, off, 16);
      if ((tid & 15) == 0) g_rowsum[i] = rs;
    }
  } else if (bid == 40) {
    // weight frag packing: frag (nt,kt): lane l elem j = W[nt*16+(l&15)][kt*32+8*(l>>4)+j]
    for (int tile = wt; tile < 24; tile += 4) {
      const int nt = tile >> 1, kt = tile & 1;
      const int wrow = nt * 16 + (l & 15);
      const int kc = kt * 32 + ((l >> 4) << 3);
      const float* s2 = W_ih + wrow * 66 + kc;
      const float* s1 = W_hh + wrow * 64 + kc;
#pragma unroll
      for (int j = 0; j < 8; ++j) {
        g_w[tile * 512 + l * 8 + j] = (f16)s2[j];
        g_w[12288 + tile * 512 + l * 8 + j] = (f16)s1[j];
      }
    }
    for (int tile = wt; tile < 8; tile += 4) {
      const int nt = tile >> 1, kt = tile & 1;
      const int wrow = nt * 16 + (l & 15);
      const int kc = kt * 32 + ((l >> 4) << 3);
      const float* s1 = W_msg + wrow * 64 + kc;
#pragma unroll
      for (int j = 0; j < 8; ++j) g_w[24576 + tile * 512 + l * 8 + j] = (f16)s1[j];
    }
    if (tid < G3) {
      g_f[tid * 2] = W_ih[tid * 66 + 64];
      g_f[tid * 2 + 1] = W_ih[tid * 66 + 65];
      g_f[384 + tid] = b_ih[tid];
      g_f[576 + tid] = b_hh[tid];
    }
    if (tid < 64) g_f[768 + tid] = b_msg[tid];
  }
}

// ---------------------------------------------------------------------------
// agg: s[i][col] = sum_j adjpos[j][i] * h[j][col]   (dense, split-fp16 MFMA)
// grid 512: bi = bx>>6 (i-tile 64), bc = bx&63 (col-tile 64)
// ---------------------------------------------------------------------------
__global__ __launch_bounds__(256, 2) void agg_kernel(
    const float* __restrict__ h_src, const f16* __restrict__ g_atf,
    float* __restrict__ s_out) {
  __shared__ float hbuf[2][32 * 66];   // 32 j x 64 cols fp32, pad stride 66
  const int bx = blockIdx.x, tid = threadIdx.x, l = tid & 63, wt = tid >> 6;
  const int bi = bx >> 6, bc = bx & 63;
  const int c0 = bc << 6;
  const int it = (bi << 2) + wt;       // 16-row i-subtile per wave

  const int sj = tid >> 3;             // staging row 0..31
  const int sc = (tid & 7) << 3;       // staging col 0..56
  const float* gsrc = h_src + c0 + sc;

  f32x4 cacc[4];
#pragma unroll
  for (int nt = 0; nt < 4; ++nt) cacc[nt] = (f32x4){0.f, 0.f, 0.f, 0.f};

  {  // prologue stage kt=0
    const float4 r0 = *(const float4*)(gsrc + sj * 4096);
    const float4 r1 = *(const float4*)(gsrc + sj * 4096 + 4);
    *(float4*)&hbuf[0][sj * 66 + sc] = r0;
    *(float4*)&hbuf[0][sj * 66 + sc + 4] = r1;
  }
  __syncthreads();

  const int jb = (l >> 4) << 3;
  const int cl = l & 15;

  for (int kt = 0; kt < 16; ++kt) {
    const int cur = kt & 1;
    float4 r0, r1;
    if (kt < 15) {   // issue next-tile loads early (write after compute)
      const float* gs = gsrc + ((kt + 1) * 32 + sj) * 4096;
      r0 = *(const float4*)(gs);
      r1 = *(const float4*)(gs + 4);
    }
    const f16x8 ahi = *(const f16x8*)(g_atf + ((it * 16 + kt) * 2 + 0) * 512 + l * 8);
    const f16x8 alo = *(const f16x8*)(g_atf + ((it * 16 + kt) * 2 + 1) * 512 + l * 8);
#pragma unroll
    for (int nt = 0; nt < 4; ++nt) {
      const float* bp = &hbuf[cur][jb * 66 + nt * 16 + cl];
      f16x8 bhi, blo;
#pragma unroll
      for (int e = 0; e < 8; ++e) {
        const float v = bp[e * 66];
        const f16 h = (f16)v;
        bhi[e] = h;
        blo[e] = (f16)(v - (float)h);
      }
      cacc[nt] = __builtin_amdgcn_mfma_f32_16x16x32_f16(ahi, bhi, cacc[nt], 0, 0, 0);
      cacc[nt] = __builtin_amdgcn_mfma_f32_16x16x32_f16(alo, bhi, cacc[nt], 0, 0, 0);
      cacc[nt] = __builtin_amdgcn_mfma_f32_16x16x32_f16(ahi, blo, cacc[nt], 0, 0, 0);
    }
    if (kt < 15) {
      const int nxt = cur ^ 1;
      *(float4*)&hbuf[nxt][sj * 66 + sc] = r0;
      *(float4*)&hbuf[nxt][sj * 66 + sc + 4] = r1;
    }
    __syncthreads();   // staged writes visible; all reads of cur done
  }

  const int ib = (it << 4) + ((l >> 4) << 2);
#pragma unroll
  for (int nt = 0; nt < 4; ++nt) {
    const int col = c0 + (nt << 4) + cl;
#pragma unroll
    for (int g = 0; g < 4; ++g)
      s_out[(ib + g) * 4096 + col] = cacc[nt][g];   // 16-lane groups -> 64B lines
  }
}

// ---------------------------------------------------------------------------
// step: m = s@W_msg^T + rowsum*b_msg ; gi = [m,x]@W_ih^T ; gh = h@W_hh^T ;
// GRU gates fp32; t==11 folds out = h@W_out^T + b_out.  block = node n.
// ---------------------------------------------------------------------------
__global__ __launch_bounds__(256, 2) void step_kernel(
    const float* __restrict__ xin, const float* __restrict__ h_src,
    float* __restrict__ h_ws, const float* __restrict__ s_in,
    const uint4* __restrict__ g_blob, const float* __restrict__ g_rowsum,
    const float* __restrict__ W_out, const float* __restrict__ b_out,
    float* __restrict__ out, int t) {
  __shared__ uint4 sBlob[3840];   // 61440B
  __shared__ float m_lds[4096];   // swz4 64x64 fp32 (reused for h at t==11)
  const f16* sBih = (const f16*)sBlob;
  const f16* sBhh = sBih + 12288;
  const f16* sBmsg = sBih + 24576;
  const float* sF = (const float*)(sBih + 28672);
  const float* sWx = sF;
  const float* s_bih = sF + 384;
  const float* s_bhh = sF + 576;
  const float* s_bmsg = sF + 768;

  const int n = blockIdx.x, tid = threadIdx.x, l = tid & 63, wt = tid >> 6;
  const int ar = wt * 16 + (l & 15);      // A-frag row (= b)
  const int kc = (l >> 4) << 3;           // A-frag k base

  // ---- front-loaded independent loads ----
  float x0[4], x1[4];
#pragma unroll
  for (int g = 0; g < 4; ++g) {
    const int brow = wt * 16 + ((l >> 4) << 2) + g;
    const float2 xv = *(const float2*)(xin + ((brow * Tt + t) * Nn + n) * Dd);
    x0[g] = xv.x;
    x1[g] = xv.y;
  }
  const float rsum = g_rowsum[n];
  const float* hrow = h_src + n * 4096;
  const float* srow = s_in + n * 4096;

  // s A-frags (fp32 -> hi/lo f16)
  f16x8 shi0, slo0, shi1, slo1;
  {
    const float4 q0 = *(const float4*)(srow + ar * 64 + kc);
    const float4 q1 = *(const float4*)(srow + ar * 64 + kc + 4);
    const float4 q2 = *(const float4*)(srow + ar * 64 + 32 + kc);
    const float4 q3 = *(const float4*)(srow + ar * 64 + 36 + kc);
    const float v[16] = {q0.x, q0.y, q0.z, q0.w, q1.x, q1.y, q1.z, q1.w,
                         q2.x, q2.y, q2.z, q2.w, q3.x, q3.y, q3.z, q3.w};
#pragma unroll
    for (int j = 0; j < 8; ++j) {
      f16 h = (f16)v[j];       shi0[j] = h; slo0[j] = (f16)(v[j] - (float)h);
      f16 g = (f16)v[8 + j];   shi1[j] = g; slo1[j] = (f16)(v[8 + j] - (float)g);
    }
  }
  // h A-frags
  f16x8 ahi0, alo0, ahi1, alo1;
  {
    const float4 q0 = *(const float4*)(hrow + ar * 64 + kc);
    const float4 q1 = *(const float4*)(hrow + ar * 64 + kc + 4);
    const float4 q2 = *(const float4*)(hrow + ar * 64 + 32 + kc);
    const float4 q3 = *(const float4*)(hrow + ar * 64 + 36 + kc);
    const float v[16] = {q0.x, q0.y, q0.z, q0.w, q1.x, q1.y, q1.z, q1.w,
                         q2.x, q2.y, q2.z, q2.w, q3.x, q3.y, q3.z, q3.w};
#pragma unroll
    for (int j = 0; j < 8; ++j) {
      f16 h = (f16)v[j];       ahi0[j] = h; alo0[j] = (f16)(v[j] - (float)h);
      f16 g = (f16)v[8 + j];   ahi1[j] = g; alo1[j] = (f16)(v[8 + j] - (float)g);
    }
  }
  // fp32 carry in MFMA C layout
  float hreg[4][4];
#pragma unroll
  for (int ct = 0; ct < 4; ++ct)
#pragma unroll
    for (int g = 0; g < 4; ++g) {
      const int row = wt * 16 + ((l >> 4) << 2) + g;
      hreg[ct][g] = hrow[row * 64 + ct * 16 + (l & 15)];
    }
  // blob stage
  for (int i = tid; i < 3840; i += 256) sBlob[i] = g_blob[i];
  __syncthreads();

  // ---- m = s @ W_msg^T + rsum*b_msg -> m_lds (own-wave rows) ----
  {
    f32x4 cm[4];
#pragma unroll
    for (int nt = 0; nt < 4; ++nt) {
      cm[nt] = (f32x4){0.f, 0.f, 0.f, 0.f};
      const f16x8 b0 = *(const f16x8*)(sBmsg + (nt * 2 + 0) * 512 + l * 8);
      const f16x8 b1 = *(const f16x8*)(sBmsg + (nt * 2 + 1) * 512 + l * 8);
      cm[nt] = __builtin_amdgcn_mfma_f32_16x16x32_f16(shi0, b0, cm[nt], 0, 0, 0);
      cm[nt] = __builtin_amdgcn_mfma_f32_16x16x32_f16(slo0, b0, cm[nt], 0, 0, 0);
      cm[nt] = __builtin_amdgcn_mfma_f32_16x16x32_f16(shi1, b1, cm[nt], 0, 0, 0);
      cm[nt] = __builtin_amdgcn_mfma_f32_16x16x32_f16(slo1, b1, cm[nt], 0, 0, 0);
    }
#pragma unroll
    for (int nt = 0; nt < 4; ++nt) {
      const int col = nt * 16 + (l & 15);
      const float bm = rsum * s_bmsg[col];
#pragma unroll
      for (int g = 0; g < 4; ++g) {
        const int row = wt * 16 + ((l >> 4) << 2) + g;
        *(float*)((char*)m_lds + swz4(row, col * 4)) = cm[nt][g] + bm;
      }
    }
  }
  // m A-frags (own-wave rows; in-wave lgkmcnt ordering)
  f16x8 mhi0, mlo0, mhi1, mlo1;
  {
    const float4 p0 = *(const float4*)((const char*)m_lds + swz4(ar, kc * 4));
    const float4 p1 = *(const float4*)((const char*)m_lds + swz4(ar, kc * 4 + 16));
    const float4 p2 = *(const float4*)((const char*)m_lds + swz4(ar, 128 + kc * 4));
    const float4 p3 = *(const float4*)((const char*)m_lds + swz4(ar, 128 + kc * 4 + 16));
    const float v[16] = {p0.x, p0.y, p0.z, p0.w, p1.x, p1.y, p1.z, p1.w,
                         p2.x, p2.y, p2.z, p2.w, p3.x, p3.y, p3.z, p3.w};
#pragma unroll
    for (int j = 0; j < 8; ++j) {
      f16 h = (f16)v[j];       mhi0[j] = h; mlo0[j] = (f16)(v[j] - (float)h);
      f16 g = (f16)v[8 + j];   mhi1[j] = g; mlo1[j] = (f16)(v[8 + j] - (float)g);
    }
  }

  // ---- gi/gh MFMA loop ----
  f32x4 cgi[12], cgh[12];
#pragma unroll
  for (int nt = 0; nt < 12; ++nt) {
    cgi[nt] = (f32x4){0.f, 0.f, 0.f, 0.f};
    cgh[nt] = (f32x4){0.f, 0.f, 0.f, 0.f};
  }
#pragma unroll
  for (int nt = 0; nt < 12; ++nt) {
    const f16x8 bh0 = *(const f16x8*)(sBhh + (nt * 2 + 0) * 512 + l * 8);
    const f16x8 bh1 = *(const f16x8*)(sBhh + (nt * 2 + 1) * 512 + l * 8);
    cgh[nt] = __builtin_amdgcn_mfma_f32_16x16x32_f16(ahi0, bh0, cgh[nt], 0, 0, 0);
    cgh[nt] = __builtin_amdgcn_mfma_f32_16x16x32_f16(alo0, bh0, cgh[nt], 0, 0, 0);
    cgh[nt] = __builtin_amdgcn_mfma_f32_16x16x32_f16(ahi1, bh1, cgh[nt], 0, 0, 0);
    cgh[nt] = __builtin_amdgcn_mfma_f32_16x16x32_f16(alo1, bh1, cgh[nt], 0, 0, 0);
    const f16x8 bi0 = *(const f16x8*)(sBih + (nt * 2 + 0) * 512 + l * 8);
    const f16x8 bi1 = *(const f16x8*)(sBih + (nt * 2 + 1) * 512 + l * 8);
    cgi[nt] = __builtin_amdgcn_mfma_f32_16x16x32_f16(mhi0, bi0, cgi[nt], 0, 0, 0);
    cgi[nt] = __builtin_amdgcn_mfma_f32_16x16x32_f16(mlo0, bi0, cgi[nt], 0, 0, 0);
    cgi[nt] = __builtin_amdgcn_mfma_f32_16x16x32_f16(mhi1, bi1, cgi[nt], 0, 0, 0);
    cgi[nt] = __builtin_amdgcn_mfma_f32_16x16x32_f16(mlo1, bi1, cgi[nt], 0, 0, 0);
  }

  // ---- GRU gates ----
#pragma unroll
  for (int ct = 0; ct < 4; ++ct) {
    const int colr = ct * 16 + (l & 15);
    const float wr0 = sWx[colr * 2], wr1 = sWx[colr * 2 + 1];
    const float wz0 = sWx[(colr + 64) * 2], wz1 = sWx[(colr + 64) * 2 + 1];
    const float wn0 = sWx[(colr + 128) * 2], wn1 = sWx[(colr + 128) * 2 + 1];
    const float bir = s_bih[colr], biz = s_bih[colr + 64], bin_ = s_bih[colr + 128];
    const float bhr = s_bhh[colr], bhz = s_bhh[colr + 64], bhn = s_bhh[colr + 128];
#pragma unroll
    for (int g = 0; g < 4; ++g) {
      const int row = wt * 16 + ((l >> 4) << 2) + g;
      const float gir = cgi[ct][g] + x0[g] * wr0 + x1[g] * wr1 + bir;
      const float giz = cgi[ct + 4][g] + x0[g] * wz0 + x1[g] * wz1 + biz;
      const float gin = cgi[ct + 8][g] + x0[g] * wn0 + x1[g] * wn1 + bin_;
      const float ghr = cgh[ct][g] + bhr;
      const float ghz = cgh[ct + 4][g] + bhz;
      const float ghn = cgh[ct + 8][g] + bhn;
      const float rg = 1.f / (1.f + __expf(-(gir + ghr)));
      const float zg = 1.f / (1.f + __expf(-(giz + ghz)));
      const float pa = gin + rg * ghn;
      const float e2 = __expf(-2.f * fabsf(pa));
      float th = (1.f - e2) / (1.f + e2);
      th = copysignf(th, pa);
      const float hn = (1.f - zg) * th + zg * hreg[ct][g];
      if (t < Tt - 1) {
        h_ws[n * 4096 + row * 64 + colr] = hn;   // 16-lane groups -> 64B lines
      } else {
        *(float*)((char*)m_lds + swz4(row, colr * 4)) = hn;  // own-wave rows
      }
    }
  }

  // ---- t==11: out[b,o,n] = h_new[b,:] . W_out[o,:] + b_out[o] ----
  if (t == Tt - 1) {
    f16x8 ohi0, olo0, ohi1, olo1;
    {
      const float4 p0 = *(const float4*)((const char*)m_lds + swz4(ar, kc * 4));
      const float4 p1 = *(const float4*)((const char*)m_lds + swz4(ar, kc * 4 + 16));
      const float4 p2 = *(const float4*)((const char*)m_lds + swz4(ar, 128 + kc * 4));
      const float4 p3 = *(const float4*)((const char*)m_lds + swz4(ar, 128 + kc * 4 + 16));
      const float v[16] = {p0.x, p0.y, p0.z, p0.w, p1.x, p1.y, p1.z, p1.w,
                           p2.x, p2.y, p2.z, p2.w, p3.x, p3.y, p3.z, p3.w};
#pragma unroll
      for (int j = 0; j < 8; ++j) {
        f16 h = (f16)v[j];       ohi0[j] = h; olo0[j] = (f16)(v[j] - (float)h);
        f16 g = (f16)v[8 + j];   ohi1[j] = g; olo1[j] = (f16)(v[8 + j] - (float)g);
      }
    }
    const int o = l & 15;
    f16x8 wo0 = {0, 0, 0, 0, 0, 0, 0, 0}, wo1 = {0, 0, 0, 0, 0, 0, 0, 0};
    if (o < Hh) {
      const float* wr_ = W_out + o * 64 + kc;
      const float4 w0 = *(const float4*)(wr_);
      const float4 w1 = *(const float4*)(wr_ + 4);
      const float4 w2 = *(const float4*)(wr_ + 32);
      const float4 w3 = *(const float4*)(wr_ + 36);
      wo0[0] = (f16)w0.x; wo0[1] = (f16)w0.y; wo0[2] = (f16)w0.z; wo0[3] = (f16)w0.w;
      wo0[4] = (f16)w1.x; wo0[5] = (f16)w1.y; wo0[6] = (f16)w1.z; wo0[7] = (f16)w1.w;
      wo1[0] = (f16)w2.x; wo1[1] = (f16)w2.y; wo1[2] = (f16)w2.z; wo1[3] = (f16)w2.w;
      wo1[4] = (f16)w3.x; wo1[5] = (f16)w3.y; wo1[6] = (f16)w3.z; wo1[7] = (f16)w3.w;
    }
    f32x4 c = {0.f, 0.f, 0.f, 0.f};
    c = __builtin_amdgcn_mfma_f32_16x16x32_f16(ohi0, wo0, c, 0, 0, 0);
    c = __builtin_amdgcn_mfma_f32_16x16x32_f16(olo0, wo0, c, 0, 0, 0);
    c = __builtin_amdgcn_mfma_f32_16x16x32_f16(ohi1, wo1, c, 0, 0, 0);
    c = __builtin_amdgcn_mfma_f32_16x16x32_f16(olo1, wo1, c, 0, 0, 0);
    if (o < Hh) {
      const float bo_ = b_out[o];
#pragma unroll
      for (int g = 0; g < 4; ++g) {
        const int b = wt * 16 + ((l >> 4) << 2) + g;
        out[(b * Hh + o) * Nn + n] = c[g] + bo_;
      }
    }
  }
}

extern "C" void kernel_launch(void* const* d_in, const int* in_sizes, int n_in,
                              void* d_out, int out_size, void* d_ws, size_t ws_size,
                              hipStream_t stream) {
  const float* xin = (const float*)d_in[0];
  const float* h0 = (const float*)d_in[1];
  const float* adj = (const float*)d_in[2];
  const float* W_msg = (const float*)d_in[3];
  const float* b_msg = (const float*)d_in[4];
  const float* W_ih = (const float*)d_in[5];
  const float* W_hh = (const float*)d_in[6];
  const float* b_ih = (const float*)d_in[7];
  const float* b_hh = (const float*)d_in[8];
  const float* W_out = (const float*)d_in[9];
  const float* b_out = (const float*)d_in[10];
  float* out = (float*)d_out;

  // ws: [0,8M) h fp32 | [8M,16M) s fp32 | [16M,17M) g_atf f16 |
  //     17M: g_blob 61440B (g_w 57344 + g_f 3328 + pad) | +61440: rowsum
  char* ws = (char*)d_ws;
  float* h_ws = (float*)ws;
  float* s_buf = (float*)(ws + (8u << 20));
  f16* g_atf = (f16*)(ws + (16u << 20));
  char* base = ws + (17u << 20);
  f16* g_w = (f16*)base;
  float* g_f = (float*)(base + 57344);
  float* g_rowsum = (float*)(base + 61440);
  const uint4* g_blob = (const uint4*)base;

  init_kernel<<<48, 256, 0, stream>>>(adj, W_msg, W_ih, W_hh, b_ih, b_hh,
                                      b_msg, g_atf, g_rowsum, g_w, g_f);
  for (int t = 0; t < Tt; ++t) {
    const float* hs = (t == 0) ? h0 : h_ws;
    agg_kernel<<<512, 256, 0, stream>>>(hs, g_atf, s_buf);
    step_kernel<<<Nn, 256, 0, stream>>>(xin, hs, h_ws, s_buf, g_blob,
                                        g_rowsum, W_out, b_out, out, t);
  }
}

// Round 7
// 487.324 us; speedup vs baseline: 1.2623x; 1.0036x over previous
//
#include <hip/hip_runtime.h>

#define Bb 64
#define Tt 12
#define Nn 512
#define Dd 2
#define G3 192
#define Hh 12

typedef float f32x4 __attribute__((ext_vector_type(4)));
typedef _Float16 f16;
typedef _Float16 f16x8 __attribute__((ext_vector_type(8)));

// XOR swizzle for 64x64 fp32 LDS tile (row stride 256B), 16B-granular.
__device__ __forceinline__ int swz4(int row, int bo) {
  return row * 256 + (bo ^ ((row & 7) << 4));
}

// ---------------------------------------------------------------------------
// init: A_pos^T hi/lo fp16 fragments (exact split), rowsum, fp16 weight frags.
// g_atf[((it*16+kt)*2+plane)*512 + l*8 + e] = adjpos[j=kt*32+8*(l>>4)+e][i=it*16+(l&15)]
// g_blob: [0,57344) f16 frags (W_ih^T | W_hh^T @12288 | W_msg^T @24576)
//         [57344,60672) fp32 extras (sWx | b_ih | b_hh | b_msg)
// ---------------------------------------------------------------------------
__global__ __launch_bounds__(256) void init_kernel(
    const float* __restrict__ adj, const float* __restrict__ W_msg,
    const float* __restrict__ W_ih, const float* __restrict__ W_hh,
    const float* __restrict__ b_ih, const float* __restrict__ b_hh,
    const float* __restrict__ b_msg, f16* __restrict__ g_atf,
    float* __restrict__ g_rowsum, f16* __restrict__ g_w,
    float* __restrict__ g_f) {
  const int bid = blockIdx.x, tid = threadIdx.x, l = tid & 63, wt = tid >> 6;
  if (bid < 32) {
    const int it = bid;
    for (int kt = wt; kt < 16; kt += 4) {
      const int i = (it << 4) + (l & 15);
      const int j0 = (kt << 5) + ((l >> 4) << 3);
      f16* dhi = g_atf + ((it * 16 + kt) * 2 + 0) * 512 + l * 8;
      f16* dlo = g_atf + ((it * 16 + kt) * 2 + 1) * 512 + l * 8;
#pragma unroll
      for (int e = 0; e < 8; ++e) {
        float a = adj[(j0 + e) * Nn + i];
        a = a > 0.f ? a : 0.f;
        const f16 h = (f16)a;
        dhi[e] = h;
        dlo[e] = (f16)(a - (float)h);
      }
    }
    // rowsum[i] = sum_j adjpos[j][i]
    {
      const int i = (it << 4) + (tid >> 4);
      float rs = 0.f;
      for (int j = (tid & 15); j < Nn; j += 16) {
        const float a = adj[j * Nn + i];
        rs += (a > 0.f ? a : 0.f);
      }
      for (int off = 8; off; off >>= 1) rs += __shfl_down(rs, off, 16);
      if ((tid & 15) == 0) g_rowsum[i] = rs;
    }
  } else if (bid == 40) {
    // weight frag packing: frag (nt,kt): lane l elem j = W[nt*16+(l&15)][kt*32+8*(l>>4)+j]
    for (int tile = wt; tile < 24; tile += 4) {
      const int nt = tile >> 1, kt = tile & 1;
      const int wrow = nt * 16 + (l & 15);
      const int kc = kt * 32 + ((l >> 4) << 3);
      const float* s2 = W_ih + wrow * 66 + kc;
      const float* s1 = W_hh + wrow * 64 + kc;
#pragma unroll
      for (int j = 0; j < 8; ++j) {
        g_w[tile * 512 + l * 8 + j] = (f16)s2[j];
        g_w[12288 + tile * 512 + l * 8 + j] = (f16)s1[j];
      }
    }
    for (int tile = wt; tile < 8; tile += 4) {
      const int nt = tile >> 1, kt = tile & 1;
      const int wrow = nt * 16 + (l & 15);
      const int kc = kt * 32 + ((l >> 4) << 3);
      const float* s1 = W_msg + wrow * 64 + kc;
#pragma unroll
      for (int j = 0; j < 8; ++j) g_w[24576 + tile * 512 + l * 8 + j] = (f16)s1[j];
    }
    if (tid < G3) {
      g_f[tid * 2] = W_ih[tid * 66 + 64];
      g_f[tid * 2 + 1] = W_ih[tid * 66 + 65];
      g_f[384 + tid] = b_ih[tid];
      g_f[576 + tid] = b_hh[tid];
    }
    if (tid < 64) g_f[768 + tid] = b_msg[tid];
  }
}

// ---------------------------------------------------------------------------
// agg: s[i][col] = sum_j adjpos[j][i] * h[j][col]   (dense, split-fp16 MFMA)
// grid 512: bi = bx>>6 (i-tile 64), bc = bx&63 (col-tile 64).
// B-frags loaded DIRECTLY from global h (64B-coalesced per 16-lane group);
// no LDS, no barriers. A-frags pre-split hi/lo in g_atf.
// ---------------------------------------------------------------------------
__global__ __launch_bounds__(256, 2) void agg_kernel(
    const float* __restrict__ h_src, const f16* __restrict__ g_atf,
    float* __restrict__ s_out) {
  const int bx = blockIdx.x, tid = threadIdx.x, l = tid & 63, wt = tid >> 6;
  const int bi = bx >> 6, bc = bx & 63;
  const int c0 = bc << 6;
  const int it = (bi << 2) + wt;       // 16-row i-subtile per wave

  const int cl = l & 15;
  const int jk = (l >> 4) << 3;        // k base within 32-tile
  const float* hp = h_src + (size_t)jk * 4096 + c0 + cl;
  const f16* ap = g_atf + (it * 16) * 2 * 512 + l * 8;

  f32x4 acc[4];
#pragma unroll
  for (int nt = 0; nt < 4; ++nt) acc[nt] = (f32x4){0.f, 0.f, 0.f, 0.f};

#pragma unroll 4
  for (int kt = 0; kt < 16; ++kt) {
    // 32 direct global loads (4 nt x 8 e), coalesced 64B per 16-lane group
    float v[32];
#pragma unroll
    for (int nt = 0; nt < 4; ++nt)
#pragma unroll
      for (int e = 0; e < 8; ++e)
        v[nt * 8 + e] = hp[(size_t)(kt * 32 + e) * 4096 + nt * 16];

    const f16x8 ahi = *(const f16x8*)(ap + (kt * 2 + 0) * 512);
    const f16x8 alo = *(const f16x8*)(ap + (kt * 2 + 1) * 512);
#pragma unroll
    for (int nt = 0; nt < 4; ++nt) {
      f16x8 bhi, blo;
#pragma unroll
      for (int e = 0; e < 8; ++e) {
        const float x = v[nt * 8 + e];
        const f16 h = (f16)x;
        bhi[e] = h;
        blo[e] = (f16)(x - (float)h);
      }
      acc[nt] = __builtin_amdgcn_mfma_f32_16x16x32_f16(ahi, bhi, acc[nt], 0, 0, 0);
      acc[nt] = __builtin_amdgcn_mfma_f32_16x16x32_f16(alo, bhi, acc[nt], 0, 0, 0);
      acc[nt] = __builtin_amdgcn_mfma_f32_16x16x32_f16(ahi, blo, acc[nt], 0, 0, 0);
    }
  }

  const int ib = (it << 4) + ((l >> 4) << 2);
#pragma unroll
  for (int nt = 0; nt < 4; ++nt) {
    const int col = c0 + (nt << 4) + cl;
#pragma unroll
    for (int g = 0; g < 4; ++g)
      s_out[(ib + g) * 4096 + col] = acc[nt][g];   // 16-lane groups -> 64B lines
  }
}

// ---------------------------------------------------------------------------
// step: m = s@W_msg^T + rowsum*b_msg ; gi = [m,x]@W_ih^T ; gh = h@W_hh^T ;
// GRU gates fp32; t==11 folds out = h@W_out^T + b_out.  block = node n.
// ---------------------------------------------------------------------------
__global__ __launch_bounds__(256, 2) void step_kernel(
    const float* __restrict__ xin, const float* __restrict__ h_src,
    float* __restrict__ h_ws, const float* __restrict__ s_in,
    const uint4* __restrict__ g_blob, const float* __restrict__ g_rowsum,
    const float* __restrict__ W_out, const float* __restrict__ b_out,
    float* __restrict__ out, int t) {
  __shared__ uint4 sBlob[3840];   // 61440B
  __shared__ float m_lds[4096];   // swz4 64x64 fp32 (reused for h at t==11)
  const f16* sBih = (const f16*)sBlob;
  const f16* sBhh = sBih + 12288;
  const f16* sBmsg = sBih + 24576;
  const float* sF = (const float*)(sBih + 28672);
  const float* sWx = sF;
  const float* s_bih = sF + 384;
  const float* s_bhh = sF + 576;
  const float* s_bmsg = sF + 768;

  const int n = blockIdx.x, tid = threadIdx.x, l = tid & 63, wt = tid >> 6;
  const int ar = wt * 16 + (l & 15);      // A-frag row (= b)
  const int kc = (l >> 4) << 3;           // A-frag k base

  // ---- front-loaded independent loads ----
  float x0[4], x1[4];
#pragma unroll
  for (int g = 0; g < 4; ++g) {
    const int brow = wt * 16 + ((l >> 4) << 2) + g;
    const float2 xv = *(const float2*)(xin + ((brow * Tt + t) * Nn + n) * Dd);
    x0[g] = xv.x;
    x1[g] = xv.y;
  }
  const float rsum = g_rowsum[n];
  const float* hrow = h_src + n * 4096;
  const float* srow = s_in + n * 4096;

  // s A-frags (fp32 -> hi/lo f16)
  f16x8 shi0, slo0, shi1, slo1;
  {
    const float4 q0 = *(const float4*)(srow + ar * 64 + kc);
    const float4 q1 = *(const float4*)(srow + ar * 64 + kc + 4);
    const float4 q2 = *(const float4*)(srow + ar * 64 + 32 + kc);
    const float4 q3 = *(const float4*)(srow + ar * 64 + 36 + kc);
    const float v[16] = {q0.x, q0.y, q0.z, q0.w, q1.x, q1.y, q1.z, q1.w,
                         q2.x, q2.y, q2.z, q2.w, q3.x, q3.y, q3.z, q3.w};
#pragma unroll
    for (int j = 0; j < 8; ++j) {
      f16 h = (f16)v[j];       shi0[j] = h; slo0[j] = (f16)(v[j] - (float)h);
      f16 g = (f16)v[8 + j];   shi1[j] = g; slo1[j] = (f16)(v[8 + j] - (float)g);
    }
  }
  // h A-frags
  f16x8 ahi0, alo0, ahi1, alo1;
  {
    const float4 q0 = *(const float4*)(hrow + ar * 64 + kc);
    const float4 q1 = *(const float4*)(hrow + ar * 64 + kc + 4);
    const float4 q2 = *(const float4*)(hrow + ar * 64 + 32 + kc);
    const float4 q3 = *(const float4*)(hrow + ar * 64 + 36 + kc);
    const float v[16] = {q0.x, q0.y, q0.z, q0.w, q1.x, q1.y, q1.z, q1.w,
                         q2.x, q2.y, q2.z, q2.w, q3.x, q3.y, q3.z, q3.w};
#pragma unroll
    for (int j = 0; j < 8; ++j) {
      f16 h = (f16)v[j];       ahi0[j] = h; alo0[j] = (f16)(v[j] - (float)h);
      f16 g = (f16)v[8 + j];   ahi1[j] = g; alo1[j] = (f16)(v[8 + j] - (float)g);
    }
  }
  // fp32 carry in MFMA C layout
  float hreg[4][4];
#pragma unroll
  for (int ct = 0; ct < 4; ++ct)
#pragma unroll
    for (int g = 0; g < 4; ++g) {
      const int row = wt * 16 + ((l >> 4) << 2) + g;
      hreg[ct][g] = hrow[row * 64 + ct * 16 + (l & 15)];
    }
  // blob stage
  for (int i = tid; i < 3840; i += 256) sBlob[i] = g_blob[i];
  __syncthreads();

  // ---- m = s @ W_msg^T + rsum*b_msg -> m_lds (own-wave rows) ----
  {
    f32x4 cm[4];
#pragma unroll
    for (int nt = 0; nt < 4; ++nt) {
      cm[nt] = (f32x4){0.f, 0.f, 0.f, 0.f};
      const f16x8 b0 = *(const f16x8*)(sBmsg + (nt * 2 + 0) * 512 + l * 8);
      const f16x8 b1 = *(const f16x8*)(sBmsg + (nt * 2 + 1) * 512 + l * 8);
      cm[nt] = __builtin_amdgcn_mfma_f32_16x16x32_f16(shi0, b0, cm[nt], 0, 0, 0);
      cm[nt] = __builtin_amdgcn_mfma_f32_16x16x32_f16(slo0, b0, cm[nt], 0, 0, 0);
      cm[nt] = __builtin_amdgcn_mfma_f32_16x16x32_f16(shi1, b1, cm[nt], 0, 0, 0);
      cm[nt] = __builtin_amdgcn_mfma_f32_16x16x32_f16(slo1, b1, cm[nt], 0, 0, 0);
    }
#pragma unroll
    for (int nt = 0; nt < 4; ++nt) {
      const int col = nt * 16 + (l & 15);
      const float bm = rsum * s_bmsg[col];
#pragma unroll
      for (int g = 0; g < 4; ++g) {
        const int row = wt * 16 + ((l >> 4) << 2) + g;
        *(float*)((char*)m_lds + swz4(row, col * 4)) = cm[nt][g] + bm;
      }
    }
  }
  // m A-frags (own-wave rows; in-wave lgkmcnt ordering)
  f16x8 mhi0, mlo0, mhi1, mlo1;
  {
    const float4 p0 = *(const float4*)((const char*)m_lds + swz4(ar, kc * 4));
    const float4 p1 = *(const float4*)((const char*)m_lds + swz4(ar, kc * 4 + 16));
    const float4 p2 = *(const float4*)((const char*)m_lds + swz4(ar, 128 + kc * 4));
    const float4 p3 = *(const float4*)((const char*)m_lds + swz4(ar, 128 + kc * 4 + 16));
    const float v[16] = {p0.x, p0.y, p0.z, p0.w, p1.x, p1.y, p1.z, p1.w,
                         p2.x, p2.y, p2.z, p2.w, p3.x, p3.y, p3.z, p3.w};
#pragma unroll
    for (int j = 0; j < 8; ++j) {
      f16 h = (f16)v[j];       mhi0[j] = h; mlo0[j] = (f16)(v[j] - (float)h);
      f16 g = (f16)v[8 + j];   mhi1[j] = g; mlo1[j] = (f16)(v[8 + j] - (float)g);
    }
  }

  // ---- gi/gh MFMA loop ----
  f32x4 cgi[12], cgh[12];
#pragma unroll
  for (int nt = 0; nt < 12; ++nt) {
    cgi[nt] = (f32x4){0.f, 0.f, 0.f, 0.f};
    cgh[nt] = (f32x4){0.f, 0.f, 0.f, 0.f};
  }
#pragma unroll
  for (int nt = 0; nt < 12; ++nt) {
    const f16x8 bh0 = *(const f16x8*)(sBhh + (nt * 2 + 0) * 512 + l * 8);
    const f16x8 bh1 = *(const f16x8*)(sBhh + (nt * 2 + 1) * 512 + l * 8);
    cgh[nt] = __builtin_amdgcn_mfma_f32_16x16x32_f16(ahi0, bh0, cgh[nt], 0, 0, 0);
    cgh[nt] = __builtin_amdgcn_mfma_f32_16x16x32_f16(alo0, bh0, cgh[nt], 0, 0, 0);
    cgh[nt] = __builtin_amdgcn_mfma_f32_16x16x32_f16(ahi1, bh1, cgh[nt], 0, 0, 0);
    cgh[nt] = __builtin_amdgcn_mfma_f32_16x16x32_f16(alo1, bh1, cgh[nt], 0, 0, 0);
    const f16x8 bi0 = *(const f16x8*)(sBih + (nt * 2 + 0) * 512 + l * 8);
    const f16x8 bi1 = *(const f16x8*)(sBih + (nt * 2 + 1) * 512 + l * 8);
    cgi[nt] = __builtin_amdgcn_mfma_f32_16x16x32_f16(mhi0, bi0, cgi[nt], 0, 0, 0);
    cgi[nt] = __builtin_amdgcn_mfma_f32_16x16x32_f16(mlo0, bi0, cgi[nt], 0, 0, 0);
    cgi[nt] = __builtin_amdgcn_mfma_f32_16x16x32_f16(mhi1, bi1, cgi[nt], 0, 0, 0);
    cgi[nt] = __builtin_amdgcn_mfma_f32_16x16x32_f16(mlo1, bi1, cgi[nt], 0, 0, 0);
  }

  // ---- GRU gates ----
#pragma unroll
  for (int ct = 0; ct < 4; ++ct) {
    const int colr = ct * 16 + (l & 15);
    const float wr0 = sWx[colr * 2], wr1 = sWx[colr * 2 + 1];
    const float wz0 = sWx[(colr + 64) * 2], wz1 = sWx[(colr + 64) * 2 + 1];
    const float wn0 = sWx[(colr + 128) * 2], wn1 = sWx[(colr + 128) * 2 + 1];
    const float bir = s_bih[colr], biz = s_bih[colr + 64], bin_ = s_bih[colr + 128];
    const float bhr = s_bhh[colr], bhz = s_bhh[colr + 64], bhn = s_bhh[colr + 128];
#pragma unroll
    for (int g = 0; g < 4; ++g) {
      const int row = wt * 16 + ((l >> 4) << 2) + g;
      const float gir = cgi[ct][g] + x0[g] * wr0 + x1[g] * wr1 + bir;
      const float giz = cgi[ct + 4][g] + x0[g] * wz0 + x1[g] * wz1 + biz;
      const float gin = cgi[ct + 8][g] + x0[g] * wn0 + x1[g] * wn1 + bin_;
      const float ghr = cgh[ct][g] + bhr;
      const float ghz = cgh[ct + 4][g] + bhz;
      const float ghn = cgh[ct + 8][g] + bhn;
      const float rg = 1.f / (1.f + __expf(-(gir + ghr)));
      const float zg = 1.f / (1.f + __expf(-(giz + ghz)));
      const float pa = gin + rg * ghn;
      const float e2 = __expf(-2.f * fabsf(pa));
      float th = (1.f - e2) / (1.f + e2);
      th = copysignf(th, pa);
      const float hn = (1.f - zg) * th + zg * hreg[ct][g];
      if (t < Tt - 1) {
        h_ws[n * 4096 + row * 64 + colr] = hn;   // 16-lane groups -> 64B lines
      } else {
        *(float*)((char*)m_lds + swz4(row, colr * 4)) = hn;  // own-wave rows
      }
    }
  }

  // ---- t==11: out[b,o,n] = h_new[b,:] . W_out[o,:] + b_out[o] ----
  if (t == Tt - 1) {
    f16x8 ohi0, olo0, ohi1, olo1;
    {
      const float4 p0 = *(const float4*)((const char*)m_lds + swz4(ar, kc * 4));
      const float4 p1 = *(const float4*)((const char*)m_lds + swz4(ar, kc * 4 + 16));
      const float4 p2 = *(const float4*)((const char*)m_lds + swz4(ar, 128 + kc * 4));
      const float4 p3 = *(const float4*)((const char*)m_lds + swz4(ar, 128 + kc * 4 + 16));
      const float v[16] = {p0.x, p0.y, p0.z, p0.w, p1.x, p1.y, p1.z, p1.w,
                           p2.x, p2.y, p2.z, p2.w, p3.x, p3.y, p3.z, p3.w};
#pragma unroll
      for (int j = 0; j < 8; ++j) {
        f16 h = (f16)v[j];       ohi0[j] = h; olo0[j] = (f16)(v[j] - (float)h);
        f16 g = (f16)v[8 + j];   ohi1[j] = g; olo1[j] = (f16)(v[8 + j] - (float)g);
      }
    }
    const int o = l & 15;
    f16x8 wo0 = {0, 0, 0, 0, 0, 0, 0, 0}, wo1 = {0, 0, 0, 0, 0, 0, 0, 0};
    if (o < Hh) {
      const float* wr_ = W_out + o * 64 + kc;
      const float4 w0 = *(const float4*)(wr_);
      const float4 w1 = *(const float4*)(wr_ + 4);
      const float4 w2 = *(const float4*)(wr_ + 32);
      const float4 w3 = *(const float4*)(wr_ + 36);
      wo0[0] = (f16)w0.x; wo0[1] = (f16)w0.y; wo0[2] = (f16)w0.z; wo0[3] = (f16)w0.w;
      wo0[4] = (f16)w1.x; wo0[5] = (f16)w1.y; wo0[6] = (f16)w1.z; wo0[7] = (f16)w1.w;
      wo1[0] = (f16)w2.x; wo1[1] = (f16)w2.y; wo1[2] = (f16)w2.z; wo1[3] = (f16)w2.w;
      wo1[4] = (f16)w3.x; wo1[5] = (f16)w3.y; wo1[6] = (f16)w3.z; wo1[7] = (f16)w3.w;
    }
    f32x4 c = {0.f, 0.f, 0.f, 0.f};
    c = __builtin_amdgcn_mfma_f32_16x16x32_f16(ohi0, wo0, c, 0, 0, 0);
    c = __builtin_amdgcn_mfma_f32_16x16x32_f16(olo0, wo0, c, 0, 0, 0);
    c = __builtin_amdgcn_mfma_f32_16x16x32_f16(ohi1, wo1, c, 0, 0, 0);
    c = __builtin_amdgcn_mfma_f32_16x16x32_f16(olo1, wo1, c, 0, 0, 0);
    if (o < Hh) {
      const float bo_ = b_out[o];
#pragma unroll
      for (int g = 0; g < 4; ++g) {
        const int b = wt * 16 + ((l >> 4) << 2) + g;
        out[(b * Hh + o) * Nn + n] = c[g] + bo_;
      }
    }
  }
}

extern "C" void kernel_launch(void* const* d_in, const int* in_sizes, int n_in,
                              void* d_out, int out_size, void* d_ws, size_t ws_size,
                              hipStream_t stream) {
  const float* xin = (const float*)d_in[0];
  const float* h0 = (const float*)d_in[1];
  const float* adj = (const float*)d_in[2];
  const float* W_msg = (const float*)d_in[3];
  const float* b_msg = (const float*)d_in[4];
  const float* W_ih = (const float*)d_in[5];
  const float* W_hh = (const float*)d_in[6];
  const float* b_ih = (const float*)d_in[7];
  const float* b_hh = (const float*)d_in[8];
  const float* W_out = (const float*)d_in[9];
  const float* b_out = (const float*)d_in[10];
  float* out = (float*)d_out;

  // ws: [0,8M) h fp32 | [8M,16M) s fp32 | [16M,17M) g_atf f16 |
  //     17M: g_blob 61440B (g_w 57344 + g_f 3328 + pad) | +61440: rowsum
  char* ws = (char*)d_ws;
  float* h_ws = (float*)ws;
  float* s_buf = (float*)(ws + (8u << 20));
  f16* g_atf = (f16*)(ws + (16u << 20));
  char* base = ws + (17u << 20);
  f16* g_w = (f16*)base;
  float* g_f = (float*)(base + 57344);
  float* g_rowsum = (float*)(base + 61440);
  const uint4* g_blob = (const uint4*)base;

  init_kernel<<<48, 256, 0, stream>>>(adj, W_msg, W_ih, W_hh, b_ih, b_hh,
                                      b_msg, g_atf, g_rowsum, g_w, g_f);
  for (int t = 0; t < Tt; ++t) {
    const float* hs = (t == 0) ? h0 : h_ws;
    agg_kernel<<<512, 256, 0, stream>>>(hs, g_atf, s_buf);
    step_kernel<<<Nn, 256, 0, stream>>>(xin, hs, h_ws, s_buf, g_blob,
                                        g_rowsum, W_out, b_out, out, t);
  }
}